// Round 1
// baseline (888.203 us; speedup 1.0000x reference)
//
#include <hip/hip_runtime.h>
#include <cstdint>

#define BATCH 8
#define NPTS  4096
#define MPTS  1024
#define DIM   64

// -------------------- Kernel 1: farthest point sampling --------------------
// One block per cloud. 512 threads; each thread owns 8 points (strided by 512).
// Coordinates live in registers AND in LDS (for the broadcast read of the
// last-selected point). Packed-u64 argmax: (float_bits(mind) << 32) | ~idx
// -> max picks largest mind, tie -> smallest idx (matches np.argmax).
__global__ __launch_bounds__(512) void fps_kernel(const float* __restrict__ pos,
                                                  int* __restrict__ gidx) {
#pragma clang fp contract(off)
  const int b = blockIdx.x;
  const int t = threadIdx.x;
  const float* p = pos + (size_t)b * NPTS * 3;

  __shared__ float sx[NPTS], sy[NPTS], sz[NPTS];
  __shared__ unsigned long long red[2][8];

  float px[8], py[8], pz[8], mind[8];
  unsigned int nidx[8];
#pragma unroll
  for (int k = 0; k < 8; ++k) {
    const int i = t + k * 512;
    const float a = p[3 * i + 0];
    const float bb = p[3 * i + 1];
    const float c = p[3 * i + 2];
    sx[i] = a; sy[i] = bb; sz[i] = c;
    px[k] = a; py[k] = bb; pz[k] = c;
    mind[k] = 3.402823466e+38f;           // finfo(float32).max
    nidx[k] = ~(unsigned int)i;           // tie-break: larger ~idx = smaller idx
  }
  __syncthreads();

  if (t == 0) gidx[b * MPTS] = b * NPTS;  // deterministic start at local idx 0

  int last = 0;
  for (int it = 1; it < MPTS; ++it) {
    const float lx = sx[last], ly = sy[last], lz = sz[last];
    unsigned long long best = 0ull;
#pragma unroll
    for (int k = 0; k < 8; ++k) {
      const float dx = __fsub_rn(px[k], lx);
      const float dy = __fsub_rn(py[k], ly);
      const float dz = __fsub_rn(pz[k], lz);
      // strict fp32, no FMA contraction: ((dx*dx + dy*dy) + dz*dz)
      const float d = __fadd_rn(__fadd_rn(__fmul_rn(dx, dx), __fmul_rn(dy, dy)),
                                __fmul_rn(dz, dz));
      const float m = fminf(mind[k], d);
      mind[k] = m;
      const unsigned long long pk =
          (((unsigned long long)__float_as_uint(m)) << 32) | (unsigned long long)nidx[k];
      best = (pk > best) ? pk : best;
    }
    // wave (64-lane) argmax reduce
#pragma unroll
    for (int off = 32; off > 0; off >>= 1) {
      const unsigned long long o = __shfl_xor(best, off, 64);
      best = (o > best) ? o : best;
    }
    const int buf = it & 1;               // double-buffered slots: 1 barrier/iter
    if ((t & 63) == 0) red[buf][t >> 6] = best;
    __syncthreads();
    unsigned long long r = red[buf][0];
#pragma unroll
    for (int wv = 1; wv < 8; ++wv) {
      const unsigned long long o = red[buf][wv];
      r = (o > r) ? o : r;
    }
    last = (int)(~(unsigned int)r);       // low word = ~idx
    if (t == 0) gidx[b * MPTS + it] = b * NPTS + last;
  }
}

// -------------------- Kernel 2: k=1 nearest neighbor -----------------------
// grid = B*16 blocks of 256 threads; each thread owns one hr point and scans
// all M lr points staged in LDS as float4 (same-address broadcast = free).
// Packed-u64 argmin: (dist_bits<<32)|j -> min picks smallest dist, tie ->
// smallest j (matches np.argmin).
__global__ __launch_bounds__(256) void nn_kernel(const float* __restrict__ pos,
                                                 const int* __restrict__ gidx,
                                                 int* __restrict__ nng) {
#pragma clang fp contract(off)
  const int b = blockIdx.x >> 4;
  const int chunk = blockIdx.x & 15;
  const int t = threadIdx.x;

  __shared__ float4 lr[MPTS];
  for (int j = t; j < MPTS; j += 256) {
    const int g = gidx[b * MPTS + j];
    lr[j] = make_float4(pos[3 * g + 0], pos[3 * g + 1], pos[3 * g + 2], 0.0f);
  }
  __syncthreads();

  const int i = b * NPTS + chunk * 256 + t;  // global hr point index
  const float x = pos[3 * i + 0];
  const float y = pos[3 * i + 1];
  const float z = pos[3 * i + 2];

  unsigned long long best = 0xFFFFFFFFFFFFFFFFull;
#pragma unroll 4
  for (int j = 0; j < MPTS; ++j) {
    const float4 q = lr[j];
    const float dx = __fsub_rn(x, q.x);
    const float dy = __fsub_rn(y, q.y);
    const float dz = __fsub_rn(z, q.z);
    const float d = __fadd_rn(__fadd_rn(__fmul_rn(dx, dx), __fmul_rn(dy, dy)),
                              __fmul_rn(dz, dz));
    const unsigned long long pk =
        (((unsigned long long)__float_as_uint(d)) << 32) | (unsigned long long)j;
    best = (pk < best) ? pk : best;
  }
  const int j = (int)(unsigned int)best;     // low word = lr index
  nng[i] = gidx[b * MPTS + j];               // store global gather index
}

// -------------------- Kernel 3: output assembly ----------------------------
// One wave per output row. Row = [x(64) | pos(3) | x[g](64) | pos[g](3)].
// Also writes output 1 (zeros, [B*N,3]) and output 2 (batch ids as floats).
__global__ __launch_bounds__(256) void assemble_kernel(const float* __restrict__ x,
                                                       const float* __restrict__ pos,
                                                       const int* __restrict__ batch,
                                                       const int* __restrict__ nng,
                                                       float* __restrict__ out) {
  const int w = (int)((blockIdx.x * 256 + threadIdx.x) >> 6);  // row
  const int lane = threadIdx.x & 63;
  if (w >= BATCH * NPTS) return;
  const int g = nng[w];

  float* o = out + (size_t)w * 134;
  o[lane] = x[(size_t)w * DIM + lane];
  o[67 + lane] = x[(size_t)g * DIM + lane];
  if (lane < 3) {
    o[64 + lane] = pos[3 * w + lane];
    o[131 + lane] = pos[3 * g + lane];
  }

  float* o2 = out + (size_t)BATCH * NPTS * 134;   // zeros output [B*N,3]
  if (lane < 3) o2[3 * w + lane] = 0.0f;
  float* o3 = o2 + (size_t)BATCH * NPTS * 3;      // batch output [B*N]
  if (lane == 0) o3[w] = (float)batch[w];
}

// ---------------------------------------------------------------------------
extern "C" void kernel_launch(void* const* d_in, const int* in_sizes, int n_in,
                              void* d_out, int out_size, void* d_ws, size_t ws_size,
                              hipStream_t stream) {
  const float* x = (const float*)d_in[0];
  const float* pos = (const float*)d_in[1];
  const int* batch = (const int*)d_in[2];

  int* gidx = (int*)d_ws;            // [B*M] global indices of sampled points
  int* nng = gidx + BATCH * MPTS;    // [B*N] global index of nearest lr point

  float* out = (float*)d_out;

  fps_kernel<<<BATCH, 512, 0, stream>>>(pos, gidx);
  nn_kernel<<<BATCH * 16, 256, 0, stream>>>(pos, gidx, nng);
  assemble_kernel<<<(BATCH * NPTS * 64) / 256, 256, 0, stream>>>(x, pos, batch, nng, out);
}

// Round 2
// 655.556 us; speedup vs baseline: 1.3549x; 1.3549x over previous
//
#include <hip/hip_runtime.h>
#include <cstdint>

#define BATCH 8
#define NPTS  4096
#define MPTS  1024
#define DIM   64

typedef float v2f __attribute__((ext_vector_type(2)));
typedef unsigned long long u64;
typedef unsigned int u32;

__device__ __forceinline__ u64 u64_max(u64 a, u64 b) { return a > b ? a : b; }
__device__ __forceinline__ u64 u64_min(u64 a, u64 b) { return a < b ? a : b; }

// One DPP step of a 64-lane u64 max reduction. bound_ctrl=true -> invalid
// source lanes read 0, which is the identity for our packed keys (always >0).
#define WAVE_MAX_U64_STEP(x, ctrl)                                              \
  {                                                                             \
    u32 lo_ = (u32)(x), hi_ = (u32)((x) >> 32);                                 \
    u32 lo2_ = (u32)__builtin_amdgcn_update_dpp(0, (int)lo_, (ctrl), 0xf, 0xf, true); \
    u32 hi2_ = (u32)__builtin_amdgcn_update_dpp(0, (int)hi_, (ctrl), 0xf, 0xf, true); \
    u64 y_ = ((u64)hi2_ << 32) | (u64)lo2_;                                     \
    (x) = (x) > y_ ? (x) : y_;                                                  \
  }

// -------------------- Kernel 1: farthest point sampling --------------------
// One block per cloud, 256 threads (4 waves), 16 points/thread held as 8
// float2 groups (packed fp32 VALU ops, identical IEEE rounding to scalar).
// Per iteration: packed distance+min update, packed-u64 argmax
// ((dist_bits<<32)|~idx -> max = largest dist, tie -> smallest idx),
// 6-step DPP wave reduce (VALU latency, not LDS latency), lane 63 writes the
// wave slot, 1 barrier, 4-slot combine, winner coords via one broadcast
// ds_read_b128 from the float4 LDS mirror.
__global__ __launch_bounds__(256) void fps_kernel(const float* __restrict__ pos,
                                                  int* __restrict__ gidx) {
#pragma clang fp contract(off)
  const int b = blockIdx.x;
  const int t = threadIdx.x;
  const float* p = pos + (size_t)b * NPTS * 3;

  __shared__ float4 sp[NPTS];
  __shared__ u64 red[2][4];

  v2f px[8], py[8], pz[8], mind[8];
#pragma unroll
  for (int k = 0; k < 16; ++k) {
    const int i = t + k * 256;
    const float a = p[3 * i + 0];
    const float c = p[3 * i + 1];
    const float d = p[3 * i + 2];
    sp[i] = make_float4(a, c, d, 0.0f);
    px[k >> 1][k & 1] = a;
    py[k >> 1][k & 1] = c;
    pz[k >> 1][k & 1] = d;
    mind[k >> 1][k & 1] = 3.402823466e+38f;  // finfo(float32).max
  }
  __syncthreads();

  if (t == 0) gidx[b * MPTS] = b * NPTS;  // deterministic start at local idx 0
  float4 w = sp[0];
  float lx = w.x, ly = w.y, lz = w.z;

  for (int it = 1; it < MPTS; ++it) {
    const v2f vlx = {lx, lx}, vly = {ly, ly}, vlz = {lz, lz};
    u64 pg[8];
#pragma unroll
    for (int g = 0; g < 8; ++g) {
      // strict fp32, no contraction: ((dx*dx + dy*dy) + dz*dz), per element
      const v2f dx = px[g] - vlx;
      const v2f dy = py[g] - vly;
      const v2f dz = pz[g] - vlz;
      const v2f d = (dx * dx + dy * dy) + dz * dz;
      const v2f m = __builtin_elementwise_min(mind[g], d);
      mind[g] = m;
      const u64 p0 = ((u64)__float_as_uint(m[0]) << 32) | (u64)(u32)~(u32)(t + (2 * g) * 256);
      const u64 p1 = ((u64)__float_as_uint(m[1]) << 32) | (u64)(u32)~(u32)(t + (2 * g + 1) * 256);
      pg[g] = u64_max(p0, p1);  // tie -> larger ~idx = smaller idx
    }
    // thread-local tree
    const u64 b0 = u64_max(pg[0], pg[1]);
    const u64 b1 = u64_max(pg[2], pg[3]);
    const u64 b2 = u64_max(pg[4], pg[5]);
    const u64 b3 = u64_max(pg[6], pg[7]);
    u64 best = u64_max(u64_max(b0, b1), u64_max(b2, b3));

    // 64-lane wave max via DPP: rows (16) then cross-row bcasts; lane 63 final.
    WAVE_MAX_U64_STEP(best, 0x111);  // row_shr:1
    WAVE_MAX_U64_STEP(best, 0x112);  // row_shr:2
    WAVE_MAX_U64_STEP(best, 0x114);  // row_shr:4
    WAVE_MAX_U64_STEP(best, 0x118);  // row_shr:8
    WAVE_MAX_U64_STEP(best, 0x142);  // row_bcast:15
    WAVE_MAX_U64_STEP(best, 0x143);  // row_bcast:31

    const int buf = it & 1;  // double-buffered slots: 1 barrier/iter
    if ((t & 63) == 63) red[buf][t >> 6] = best;
    __syncthreads();

    const u64 r0 = red[buf][0], r1 = red[buf][1];
    const u64 r2 = red[buf][2], r3 = red[buf][3];
    const u64 c = u64_max(u64_max(r0, r1), u64_max(r2, r3));
    const u32 widx = ~(u32)c;  // low word = ~idx

    w = sp[widx];  // broadcast read (same address all lanes)
    lx = w.x; ly = w.y; lz = w.z;
    if (t == 0) gidx[b * MPTS + it] = b * NPTS + (int)widx;
  }
}

// -------------------- Kernel 2: k=1 nearest neighbor -----------------------
// B*32 blocks x 256 threads; 128 hr points per block, 2 threads per point
// splitting the M=1024 lr points in half; packed fp32 over lr pairs.
// Packed-u64 argmin: (dist_bits<<32)|j -> min = smallest dist, tie ->
// smallest j (matches np.argmin). Pair combine via one shfl_xor(1).
__global__ __launch_bounds__(256) void nn_kernel(const float* __restrict__ pos,
                                                 const int* __restrict__ gidx,
                                                 int* __restrict__ nng) {
#pragma clang fp contract(off)
  const int b = blockIdx.x >> 5;
  const int chunk = blockIdx.x & 31;
  const int t = threadIdx.x;

  __shared__ float lrx[MPTS], lry[MPTS], lrz[MPTS];
  for (int j = t; j < MPTS; j += 256) {
    const int g = gidx[b * MPTS + j];
    lrx[j] = pos[3 * g + 0];
    lry[j] = pos[3 * g + 1];
    lrz[j] = pos[3 * g + 2];
  }
  __syncthreads();

  const int pt = chunk * 128 + (t >> 1);
  const int half = t & 1;
  const int i = b * NPTS + pt;  // global hr point index
  const float x = pos[3 * i + 0];
  const float y = pos[3 * i + 1];
  const float z = pos[3 * i + 2];
  const v2f vx = {x, x}, vy = {y, y}, vz = {z, z};

  u64 best = ~0ull;
  const int j0 = half * 512;
#pragma unroll 4
  for (int s = 0; s < 256; ++s) {
    const int j = j0 + 2 * s;
    const v2f qx = *(const v2f*)&lrx[j];
    const v2f qy = *(const v2f*)&lry[j];
    const v2f qz = *(const v2f*)&lrz[j];
    const v2f dx = vx - qx;
    const v2f dy = vy - qy;
    const v2f dz = vz - qz;
    const v2f d = (dx * dx + dy * dy) + dz * dz;
    const u64 p0 = ((u64)__float_as_uint(d[0]) << 32) | (u64)(u32)j;
    const u64 p1 = ((u64)__float_as_uint(d[1]) << 32) | (u64)(u32)(j + 1);
    best = u64_min(best, u64_min(p0, p1));
  }
  const u64 o = __shfl_xor(best, 1, 64);
  best = u64_min(best, o);
  if (half == 0) nng[i] = gidx[b * MPTS + (int)(u32)best];
}

// -------------------- Kernel 3: output assembly ----------------------------
// One wave per output row. Row = [x(64) | pos(3) | x[g](64) | pos[g](3)].
// Also writes output 1 (zeros, [B*N,3]) and output 2 (batch ids as floats).
__global__ __launch_bounds__(256) void assemble_kernel(const float* __restrict__ x,
                                                       const float* __restrict__ pos,
                                                       const int* __restrict__ batch,
                                                       const int* __restrict__ nng,
                                                       float* __restrict__ out) {
  const int w = (int)((blockIdx.x * 256 + threadIdx.x) >> 6);  // row
  const int lane = threadIdx.x & 63;
  if (w >= BATCH * NPTS) return;
  const int g = nng[w];

  float* o = out + (size_t)w * 134;
  o[lane] = x[(size_t)w * DIM + lane];
  o[67 + lane] = x[(size_t)g * DIM + lane];
  if (lane < 3) {
    o[64 + lane] = pos[3 * w + lane];
    o[131 + lane] = pos[3 * g + lane];
  }

  float* o2 = out + (size_t)BATCH * NPTS * 134;  // zeros output [B*N,3]
  if (lane < 3) o2[3 * w + lane] = 0.0f;
  float* o3 = o2 + (size_t)BATCH * NPTS * 3;     // batch output [B*N]
  if (lane == 0) o3[w] = (float)batch[w];
}

// ---------------------------------------------------------------------------
extern "C" void kernel_launch(void* const* d_in, const int* in_sizes, int n_in,
                              void* d_out, int out_size, void* d_ws, size_t ws_size,
                              hipStream_t stream) {
  const float* x = (const float*)d_in[0];
  const float* pos = (const float*)d_in[1];
  const int* batch = (const int*)d_in[2];

  int* gidx = (int*)d_ws;            // [B*M] global indices of sampled points
  int* nng = gidx + BATCH * MPTS;    // [B*N] global index of nearest lr point

  float* out = (float*)d_out;

  fps_kernel<<<BATCH, 256, 0, stream>>>(pos, gidx);
  nn_kernel<<<BATCH * 32, 256, 0, stream>>>(pos, gidx, nng);
  assemble_kernel<<<(BATCH * NPTS * 64) / 256, 256, 0, stream>>>(x, pos, batch, nng, out);
}

// Round 3
// 575.757 us; speedup vs baseline: 1.5427x; 1.1386x over previous
//
#include <hip/hip_runtime.h>
#include <cstdint>

#define BATCH 8
#define NPTS  4096
#define MPTS  1024
#define DIM   64

typedef float v2f __attribute__((ext_vector_type(2)));
typedef unsigned long long u64;
typedef unsigned int u32;

// Pack (f32 distance bits, aux) into a double whose VALUE ordering equals the
// u64 bit-pattern ordering: hi word = f32 bits of a non-negative float
// (<= FLT_MAX bits 0x7F7FFFFF -> f64 exponent <= 2039, sign 0 -> positive
// finite double). So v_max_f64 / v_min_f64 (1 inst each) give exact u64
// max/min — replacing the 3-inst v_cmp_u64+2*cndmask sequence.
__device__ __forceinline__ double mk_key(float m, u32 aux) {
  const u64 k = ((u64)__float_as_uint(m) << 32) | (u64)aux;
  return __longlong_as_double((long long)k);
}
__device__ __forceinline__ u32 key_lo(double d) {
  return (u32)(u64)__double_as_longlong(d);
}

// One DPP step of a 64-lane f64-key max reduction. bound_ctrl=true -> invalid
// source lanes read 0.0, the identity for max of positive keys.
#define WAVE_MAX_F64_STEP(x, ctrl)                                                    \
  {                                                                                   \
    const u64 xu_ = (u64)__double_as_longlong(x);                                     \
    const int lo_ = __builtin_amdgcn_update_dpp(0, (int)(u32)xu_, (ctrl), 0xf, 0xf, true);  \
    const int hi_ = __builtin_amdgcn_update_dpp(0, (int)(u32)(xu_ >> 32), (ctrl), 0xf, 0xf, true); \
    const double y_ = __longlong_as_double((long long)(((u64)(u32)hi_ << 32) | (u64)(u32)lo_)); \
    (x) = fmax((x), y_);                                                              \
  }

// -------------------- Kernel 1: farthest point sampling --------------------
// One block per cloud, 256 threads (4 waves), 16 points/thread as 8 float2
// groups (v_pk_* fp32, identical IEEE rounding to scalar, contract off).
// Argmax key: (dist_bits<<32)|~idx -> max = largest dist, tie -> smallest idx
// (matches np.argmax). All 64-bit maxes via single v_max_f64 (see mk_key).
// 6-step DPP wave reduce, lane 63 writes wave slot, 1 barrier (double-buffered
// slots), 4-slot combine, winner coords via broadcast ds_read_b128.
__global__ __launch_bounds__(256) void fps_kernel(const float* __restrict__ pos,
                                                  int* __restrict__ gidx) {
#pragma clang fp contract(off)
  const int b = blockIdx.x;
  const int t = threadIdx.x;
  const float* p = pos + (size_t)b * NPTS * 3;

  __shared__ float4 sp[NPTS];
  __shared__ double red[2][4];

  v2f px[8], py[8], pz[8], mind[8];
#pragma unroll
  for (int k = 0; k < 16; ++k) {
    const int i = t + k * 256;
    const float a = p[3 * i + 0];
    const float c = p[3 * i + 1];
    const float d = p[3 * i + 2];
    sp[i] = make_float4(a, c, d, 0.0f);
    px[k >> 1][k & 1] = a;
    py[k >> 1][k & 1] = c;
    pz[k >> 1][k & 1] = d;
    mind[k >> 1][k & 1] = 3.402823466e+38f;  // finfo(float32).max
  }
  __syncthreads();

  if (t == 0) gidx[b * MPTS] = b * NPTS;  // deterministic start at local idx 0
  float4 w = sp[0];
  float lx = w.x, ly = w.y, lz = w.z;

  for (int it = 1; it < MPTS; ++it) {
    const v2f vlx = {lx, lx}, vly = {ly, ly}, vlz = {lz, lz};
    double pg[8];
#pragma unroll
    for (int g = 0; g < 8; ++g) {
      // strict fp32, no contraction: ((dx*dx + dy*dy) + dz*dz), per element
      const v2f dx = px[g] - vlx;
      const v2f dy = py[g] - vly;
      const v2f dz = pz[g] - vlz;
      const v2f d = (dx * dx + dy * dy) + dz * dz;
      const v2f m = __builtin_elementwise_min(mind[g], d);
      mind[g] = m;
      const double p0 = mk_key(m[0], ~(u32)(t + (2 * g) * 256));      // hoisted consts
      const double p1 = mk_key(m[1], ~(u32)(t + (2 * g + 1) * 256));  // tie -> larger ~idx
      pg[g] = fmax(p0, p1);
    }
    // thread-local tree (all single v_max_f64)
    const double b0 = fmax(pg[0], pg[1]);
    const double b1 = fmax(pg[2], pg[3]);
    const double b2 = fmax(pg[4], pg[5]);
    const double b3 = fmax(pg[6], pg[7]);
    double best = fmax(fmax(b0, b1), fmax(b2, b3));

    // 64-lane wave max via DPP: rows (16) then cross-row bcasts; lane 63 final.
    WAVE_MAX_F64_STEP(best, 0x111);  // row_shr:1
    WAVE_MAX_F64_STEP(best, 0x112);  // row_shr:2
    WAVE_MAX_F64_STEP(best, 0x114);  // row_shr:4
    WAVE_MAX_F64_STEP(best, 0x118);  // row_shr:8
    WAVE_MAX_F64_STEP(best, 0x142);  // row_bcast:15
    WAVE_MAX_F64_STEP(best, 0x143);  // row_bcast:31

    const int buf = it & 1;  // double-buffered slots: 1 barrier/iter
    if ((t & 63) == 63) red[buf][t >> 6] = best;
    __syncthreads();

    const double c = fmax(fmax(red[buf][0], red[buf][1]),
                          fmax(red[buf][2], red[buf][3]));
    const u32 widx = ~key_lo(c);  // low word = ~idx

    w = sp[widx];  // broadcast read (same address all lanes)
    lx = w.x; ly = w.y; lz = w.z;
    if (t == 0) gidx[b * MPTS + it] = b * NPTS + (int)widx;
  }
}

// -------------------- Kernel 2: k=1 nearest neighbor -----------------------
// B*32 blocks x 256 threads; 128 hr points per block, 2 threads per point
// splitting the M=1024 lr points in half; packed fp32 over lr pairs.
// Argmin key: (dist_bits<<32)|j -> min = smallest dist, tie -> smallest j
// (matches np.argmin); 64-bit mins via single v_min_f64. Pair combine via
// one shfl_xor(1).
__global__ __launch_bounds__(256) void nn_kernel(const float* __restrict__ pos,
                                                 const int* __restrict__ gidx,
                                                 int* __restrict__ nng) {
#pragma clang fp contract(off)
  const int b = blockIdx.x >> 5;
  const int chunk = blockIdx.x & 31;
  const int t = threadIdx.x;

  __shared__ float lrx[MPTS], lry[MPTS], lrz[MPTS];
  for (int j = t; j < MPTS; j += 256) {
    const int g = gidx[b * MPTS + j];
    lrx[j] = pos[3 * g + 0];
    lry[j] = pos[3 * g + 1];
    lrz[j] = pos[3 * g + 2];
  }
  __syncthreads();

  const int pt = chunk * 128 + (t >> 1);
  const int half = t & 1;
  const int i = b * NPTS + pt;  // global hr point index
  const float x = pos[3 * i + 0];
  const float y = pos[3 * i + 1];
  const float z = pos[3 * i + 2];
  const v2f vx = {x, x}, vy = {y, y}, vz = {z, z};

  double best = __longlong_as_double(0x7FEFFFFFFFFFFFFFll);  // +DBL_MAX > all keys
  const int j0 = half * 512;
#pragma unroll 4
  for (int s = 0; s < 256; ++s) {
    const int j = j0 + 2 * s;
    const v2f qx = *(const v2f*)&lrx[j];
    const v2f qy = *(const v2f*)&lry[j];
    const v2f qz = *(const v2f*)&lrz[j];
    const v2f dx = vx - qx;
    const v2f dy = vy - qy;
    const v2f dz = vz - qz;
    const v2f d = (dx * dx + dy * dy) + dz * dz;
    const double p0 = mk_key(d[0], (u32)j);
    const double p1 = mk_key(d[1], (u32)(j + 1));
    best = fmin(best, fmin(p0, p1));
  }
  // pair combine across the two halves (lanes differ only in bit 0)
  const u64 bu = (u64)__double_as_longlong(best);
  const u64 ou = ((u64)(u32)__shfl_xor((int)(bu >> 32), 1, 64) << 32) |
                 (u64)(u32)__shfl_xor((int)(u32)bu, 1, 64);
  best = fmin(best, __longlong_as_double((long long)ou));
  if (half == 0) nng[i] = gidx[b * MPTS + (int)key_lo(best)];
}

// -------------------- Kernel 3: output assembly ----------------------------
// One wave per output row. Row = [x(64) | pos(3) | x[g](64) | pos[g](3)].
// Also writes output 1 (zeros, [B*N,3]) and output 2 (batch ids as floats).
__global__ __launch_bounds__(256) void assemble_kernel(const float* __restrict__ x,
                                                       const float* __restrict__ pos,
                                                       const int* __restrict__ batch,
                                                       const int* __restrict__ nng,
                                                       float* __restrict__ out) {
  const int w = (int)((blockIdx.x * 256 + threadIdx.x) >> 6);  // row
  const int lane = threadIdx.x & 63;
  if (w >= BATCH * NPTS) return;
  const int g = nng[w];

  float* o = out + (size_t)w * 134;
  o[lane] = x[(size_t)w * DIM + lane];
  o[67 + lane] = x[(size_t)g * DIM + lane];
  if (lane < 3) {
    o[64 + lane] = pos[3 * w + lane];
    o[131 + lane] = pos[3 * g + lane];
  }

  float* o2 = out + (size_t)BATCH * NPTS * 134;  // zeros output [B*N,3]
  if (lane < 3) o2[3 * w + lane] = 0.0f;
  float* o3 = o2 + (size_t)BATCH * NPTS * 3;     // batch output [B*N]
  if (lane == 0) o3[w] = (float)batch[w];
}

// ---------------------------------------------------------------------------
extern "C" void kernel_launch(void* const* d_in, const int* in_sizes, int n_in,
                              void* d_out, int out_size, void* d_ws, size_t ws_size,
                              hipStream_t stream) {
  const float* x = (const float*)d_in[0];
  const float* pos = (const float*)d_in[1];
  const int* batch = (const int*)d_in[2];

  int* gidx = (int*)d_ws;            // [B*M] global indices of sampled points
  int* nng = gidx + BATCH * MPTS;    // [B*N] global index of nearest lr point

  float* out = (float*)d_out;

  fps_kernel<<<BATCH, 256, 0, stream>>>(pos, gidx);
  nn_kernel<<<BATCH * 32, 256, 0, stream>>>(pos, gidx, nng);
  assemble_kernel<<<(BATCH * NPTS * 64) / 256, 256, 0, stream>>>(x, pos, batch, nng, out);
}